// Round 6
// baseline (8320.808 us; speedup 1.0000x reference)
//
#include <hip/hip_runtime.h>
#include <hip/hip_cooperative_groups.h>
#include <math.h>

namespace cg = cooperative_groups;

#define TSTEPS 32
#define CAPL 33
#define EDIM 512
#define HDIM 512
#define VOCAB 10000
#define BATCH 64
#define RREG 49

// ---------- fast transcendentals ----------
__device__ __forceinline__ float frcp(float x) { return __builtin_amdgcn_rcpf(x); }
__device__ __forceinline__ float ftanh(float x) {
  float e = __expf(2.f * x);            // saturates correctly at +/-inf
  return 1.f - 2.f * frcp(e + 1.f);
}
__device__ __forceinline__ float fsig(float x) { return frcp(1.f + __expf(-x)); }

// ================= big-tile fp32 GEMM (prologue + vocab projection) =================
struct GemmP {
  const float* A; const float* B; const float* bias; const float* D;
  float* C; int M, N, K, lda, ldb, ldd, ldc;
  const int* caps;
};

template<bool BT, bool GATHER>
__device__ __forceinline__ void gemm_body(GemmP p, int bx, int by)
{
  __shared__ float as[32][132];
  __shared__ float bs[32][132];
  const int tid = threadIdx.x;
  const int m0 = by * 128, n0 = bx * 128;
  const int tx = tid & 15, ty = tid >> 4;
  float acc[8][8];
#pragma unroll
  for (int i = 0; i < 8; ++i)
#pragma unroll
    for (int j = 0; j < 8; ++j) acc[i][j] = 0.f;

  const int lr = tid >> 3, lf = tid & 7;
  const int nf = tid & 31, nk = tid >> 5;

  for (int k0 = 0; k0 < p.K; k0 += 32) {
#pragma unroll
    for (int q = 0; q < 4; ++q) {
      int m = m0 + lr + 32 * q;
      float4 v = make_float4(0.f, 0.f, 0.f, 0.f);
      if (m < p.M) {
        int row = m;
        if (GATHER) row = p.caps[(m >> 5) * CAPL + (m & 31)];
        v = *(const float4*)(p.A + (size_t)row * p.lda + k0 + lf * 4);
      }
      int rr = lr + 32 * q;
      as[lf * 4 + 0][rr] = v.x; as[lf * 4 + 1][rr] = v.y;
      as[lf * 4 + 2][rr] = v.z; as[lf * 4 + 3][rr] = v.w;
    }
    if (BT) {
#pragma unroll
      for (int q = 0; q < 4; ++q) {
        int n = n0 + lr + 32 * q;
        float4 v = make_float4(0.f, 0.f, 0.f, 0.f);
        if (n < p.N) v = *(const float4*)(p.B + (size_t)n * p.ldb + k0 + lf * 4);
        int rr = lr + 32 * q;
        bs[lf * 4 + 0][rr] = v.x; bs[lf * 4 + 1][rr] = v.y;
        bs[lf * 4 + 2][rr] = v.z; bs[lf * 4 + 3][rr] = v.w;
      }
    } else {
#pragma unroll
      for (int q = 0; q < 4; ++q) {
        int k = nk + 8 * q;
        int n = n0 + nf * 4;
        float4 v = make_float4(0.f, 0.f, 0.f, 0.f);
        if (n < p.N) v = *(const float4*)(p.B + (size_t)(k0 + k) * p.ldb + n);
        *(float4*)&bs[k][nf * 4] = v;
      }
    }
    __syncthreads();
#pragma unroll
    for (int k = 0; k < 32; ++k) {
      float4 a0 = *(const float4*)&as[k][ty * 4];
      float4 a1 = *(const float4*)&as[k][ty * 4 + 64];
      float4 b0 = *(const float4*)&bs[k][tx * 4];
      float4 b1 = *(const float4*)&bs[k][tx * 4 + 64];
      float av[8] = {a0.x, a0.y, a0.z, a0.w, a1.x, a1.y, a1.z, a1.w};
      float bv[8] = {b0.x, b0.y, b0.z, b0.w, b1.x, b1.y, b1.z, b1.w};
#pragma unroll
      for (int i = 0; i < 8; ++i)
#pragma unroll
        for (int j = 0; j < 8; ++j)
          acc[i][j] = fmaf(av[i], bv[j], acc[i][j]);
    }
    __syncthreads();
  }
  const bool hb = (p.bias != nullptr);
  const bool hd = (p.D != nullptr);
#pragma unroll
  for (int i = 0; i < 8; ++i) {
    int m = m0 + ty * 4 + (i & 3) + ((i >> 2) * 64);
    if (m >= p.M) continue;
#pragma unroll
    for (int jj = 0; jj < 2; ++jj) {
      int n = n0 + tx * 4 + jj * 64;
      if (n >= p.N) continue;
      float4 r;
      r.x = acc[i][jj * 4 + 0]; r.y = acc[i][jj * 4 + 1];
      r.z = acc[i][jj * 4 + 2]; r.w = acc[i][jj * 4 + 3];
      if (hb) { r.x += p.bias[n]; r.y += p.bias[n + 1]; r.z += p.bias[n + 2]; r.w += p.bias[n + 3]; }
      if (hd) {
        const float4 d = *(const float4*)(p.D + (size_t)m * p.ldd + n);
        r.x += d.x; r.y += d.y; r.z += d.z; r.w += d.w;
      }
      *(float4*)(p.C + (size_t)m * p.ldc + n) = r;
    }
  }
}

template<bool BT, bool GATHER>
__global__ __launch_bounds__(256) void gemm_k(GemmP p) {
  gemm_body<BT, GATHER>(p, blockIdx.x, blockIdx.y);
}

__global__ __launch_bounds__(256) void k_prologue(GemmP pk1, GemmP pk0) {
  if (blockIdx.z == 0) {
    if (blockIdx.x < 12 && blockIdx.y < 16) gemm_body<true, true>(pk1, blockIdx.x, blockIdx.y);
  } else {
    if (blockIdx.x < 4 && blockIdx.y < 25) gemm_body<false, false>(pk0, blockIdx.x, blockIdx.y);
  }
}

// ================= FALLBACK path kernels (round-3 verified) =================
struct GateP {
  const float* ctx; const float* h;
  const float* Wc;  const float* Wh;
  float* P;
};

__global__ __launch_bounds__(256) void k_gates(GateP g)
{
  __shared__ float as[32][68];
  __shared__ float bs[32][68];
  const int tid = threadIdx.x;
  const int n0g = blockIdx.x * 64;
  const bool hh = (n0g >= 1536);
  const float* A = hh ? g.h : g.ctx;
  const float* B = hh ? g.Wh : g.Wc;
  const int ldb = hh ? 512 : 1024;
  const int nb = hh ? (n0g - 1536) : n0g;
  const int kbase = blockIdx.z * 256;
  float* C = g.P + (size_t)blockIdx.z * 64 * 3072;

  const int tx = tid & 15, ty = tid >> 4;
  float acc[4][4] = {};
  if (A != nullptr) {
    const int lr = tid >> 3, lf = tid & 7;
    for (int k0 = kbase; k0 < kbase + 256; k0 += 32) {
      {
        float4 v = *(const float4*)(A + (size_t)lr * 512 + k0 + lf * 4);
        as[lf * 4 + 0][lr] = v.x; as[lf * 4 + 1][lr] = v.y;
        as[lf * 4 + 2][lr] = v.z; as[lf * 4 + 3][lr] = v.w;
        float4 w = *(const float4*)(A + (size_t)(lr + 32) * 512 + k0 + lf * 4);
        as[lf * 4 + 0][lr + 32] = w.x; as[lf * 4 + 1][lr + 32] = w.y;
        as[lf * 4 + 2][lr + 32] = w.z; as[lf * 4 + 3][lr + 32] = w.w;
      }
      {
        float4 v = *(const float4*)(B + (size_t)(nb + lr) * ldb + k0 + lf * 4);
        bs[lf * 4 + 0][lr] = v.x; bs[lf * 4 + 1][lr] = v.y;
        bs[lf * 4 + 2][lr] = v.z; bs[lf * 4 + 3][lr] = v.w;
        float4 w = *(const float4*)(B + (size_t)(nb + lr + 32) * ldb + k0 + lf * 4);
        bs[lf * 4 + 0][lr + 32] = w.x; bs[lf * 4 + 1][lr + 32] = w.y;
        bs[lf * 4 + 2][lr + 32] = w.z; bs[lf * 4 + 3][lr + 32] = w.w;
      }
      __syncthreads();
#pragma unroll
      for (int k = 0; k < 32; ++k) {
        float4 a = *(const float4*)&as[k][ty * 4];
        float4 b = *(const float4*)&bs[k][tx * 4];
        float av[4] = {a.x, a.y, a.z, a.w};
        float bv[4] = {b.x, b.y, b.z, b.w};
#pragma unroll
        for (int i = 0; i < 4; ++i)
#pragma unroll
          for (int j = 0; j < 4; ++j)
            acc[i][j] = fmaf(av[i], bv[j], acc[i][j]);
      }
      __syncthreads();
    }
  }
#pragma unroll
  for (int i = 0; i < 4; ++i) {
    float4 r = make_float4(acc[i][0], acc[i][1], acc[i][2], acc[i][3]);
    *(float4*)(C + (size_t)(ty * 4 + i) * 3072 + n0g + tx * 4) = r;
  }
}

__global__ __launch_bounds__(512) void k_front(
    const float* __restrict__ P, const float* __restrict__ gxx,
    const float* __restrict__ bhh, float* __restrict__ h,
    float* __restrict__ hall, const float* __restrict__ fproj,
    const float* __restrict__ features, const float* __restrict__ vw,
    const float* __restrict__ aw2, float* __restrict__ ctx, int t)
{
  __shared__ float hs[512];
  __shared__ float hp[512];
  __shared__ float sc[64];
  const int b = blockIdx.x, j = threadIdx.x;

  if (t > 0) {
    const float* p0 = P + (size_t)b * 3072;
    const float* p1 = P + (size_t)64 * 3072 + (size_t)b * 3072;
    const float* gx = gxx + ((size_t)b * TSTEPS + (t - 1)) * 1536;
    float xr = p0[j]        + p1[j]        + gx[j];
    float xz = p0[512 + j]  + p1[512 + j]  + gx[512 + j];
    float xn = p0[1024 + j] + p1[1024 + j] + gx[1024 + j];
    float hr = p0[1536 + j] + p1[1536 + j] + bhh[j];
    float hz = p0[2048 + j] + p1[2048 + j] + bhh[512 + j];
    float hn = p0[2560 + j] + p1[2560 + j] + bhh[1024 + j];
    float hold = (t == 1) ? 0.f : h[b * 512 + j];
    float r = fsig(xr + hr);
    float z = fsig(xz + hz);
    float n = ftanh(xn + r * hn);
    float hv = (1.f - z) * n + z * hold;
    h[b * 512 + j] = hv;
    hall[((size_t)b * TSTEPS + (t - 1)) * 512 + j] = hv;
    hs[j] = hv;
  } else {
    hs[j] = 0.f;
  }
  if (t == TSTEPS) return;
  if (j >= RREG && j < 64) sc[j] = -1e30f;
  __syncthreads();

  float hpv = 0.f;
  if (t > 0) {
    float a0 = 0.f, a1 = 0.f, a2 = 0.f, a3 = 0.f;
    for (int k = 0; k < 512; k += 4) {
      a0 = fmaf(hs[k + 0], aw2[(size_t)(k + 0) * 512 + j], a0);
      a1 = fmaf(hs[k + 1], aw2[(size_t)(k + 1) * 512 + j], a1);
      a2 = fmaf(hs[k + 2], aw2[(size_t)(k + 2) * 512 + j], a2);
      a3 = fmaf(hs[k + 3], aw2[(size_t)(k + 3) * 512 + j], a3);
    }
    hpv = (a0 + a1) + (a2 + a3);
  }
  hp[j] = hpv;
  __syncthreads();

  const int wv = j >> 6, lane = j & 63;
  float vwr[8], hpr[8];
#pragma unroll
  for (int c = 0; c < 8; ++c) {
    vwr[c] = vw[lane + 64 * c];
    hpr[c] = hp[lane + 64 * c];
  }
  const float* fpb = fproj + (size_t)b * RREG * 512;
  for (int i = 0; i < 7; ++i) {
    int r = wv + 8 * i;
    if (r < RREG) {
      float s = 0.f;
#pragma unroll
      for (int c = 0; c < 8; ++c)
        s += vwr[c] * ftanh(fpb[r * 512 + lane + 64 * c] + hpr[c]);
#pragma unroll
      for (int d = 32; d > 0; d >>= 1) s += __shfl_xor(s, d, 64);
      if (lane == 0) sc[r] = s;
    }
  }
  __syncthreads();
  if (wv == 0) {
    float v = sc[lane];
    float m = v;
#pragma unroll
    for (int d = 32; d > 0; d >>= 1) m = fmaxf(m, __shfl_xor(m, d, 64));
    float e = (lane < RREG) ? __expf(v - m) : 0.f;
    float ssum = e;
#pragma unroll
    for (int d = 32; d > 0; d >>= 1) ssum += __shfl_xor(ssum, d, 64);
    sc[lane] = e * frcp(ssum);
  }
  __syncthreads();
  float a = 0.f;
  const float* fb = features + (size_t)b * RREG * 512;
  for (int r = 0; r < RREG; ++r) a = fmaf(sc[r], fb[r * 512 + j], a);
  ctx[b * 512 + j] = a;
}

// ================= persistent cooperative recurrence (simplified) =================
// 256 blocks x 256 threads; 4 grid-syncs per step.
// S0 (32 blocks): GRU update, h columns sharded 16-wide; single h buffer.
// S1 (256 blocks = 32 s-chunks x 8 n-tiles): Php[s] = h[:,s-chunk] @ aw2[s-chunk, n-tile]
// S2 (64 blocks): sum Php -> hproj; scores; softmax; ctx
// S3 (96 blocks = 48 n-tiles x splitK2): gates partials P
struct LoopP {
  const float* gxx; const float* bhh;
  float* h; float* hall; float* Php; float* P; float* ctx;
  const float* fproj; const float* features; const float* vw;
  const float* aw2; const float* Wc; const float* Whh;
};

__global__ __launch_bounds__(256, 1) void k_loop2(LoopP q)
{
  cg::grid_group grid = cg::this_grid();
  __shared__ float hA[16][65];
  __shared__ float bsA[16][68];
  __shared__ float asg[32][68];
  __shared__ float bsg[32][68];
  __shared__ float hp[512];
  __shared__ float sc[64];
  const int bid = blockIdx.x, tid = threadIdx.x;

  // ---- S0: GRU update for h[:, bid*16 .. +16) (blocks 0..31 only) ----
  auto S0 = [&](int t) {
    const int s = bid;
    for (int e = tid; e < 1024; e += 256) {
      const int b = e >> 4, c = e & 15, j = s * 16 + c;
      const float* p0 = q.P + (size_t)b * 3072;
      const float* p1 = q.P + (size_t)(64 + b) * 3072;
      const float* gx = q.gxx + ((size_t)b * TSTEPS + (t - 1)) * 1536;
      float xr = p0[j]        + p1[j]        + gx[j];
      float xz = p0[512 + j]  + p1[512 + j]  + gx[512 + j];
      float xn = p0[1024 + j] + p1[1024 + j] + gx[1024 + j];
      float hr = p0[1536 + j] + p1[1536 + j] + q.bhh[j];
      float hz = p0[2048 + j] + p1[2048 + j] + q.bhh[512 + j];
      float hn = p0[2560 + j] + p1[2560 + j] + q.bhh[1024 + j];
      float hold = (t == 1) ? 0.f : q.h[b * 512 + j];
      float r = fsig(xr + hr), z = fsig(xz + hz);
      float n = ftanh(xn + r * hn);
      float hv = (1.f - z) * n + z * hold;
      q.h[b * 512 + j] = hv;
      q.hall[((size_t)b * TSTEPS + (t - 1)) * 512 + j] = hv;
    }
  };

  for (int t = 0; t < TSTEPS; ++t) {
    if (t > 0 && bid < 32) S0(t);
    __threadfence();
    grid.sync();

    // ---- S1: Php[s][:, nt*64..+64) = h-chunk @ aw2-tile ----
    if (t > 0) {
      const int s = bid & 31, nt = bid >> 5;
      for (int e = tid; e < 1024; e += 256) {
        const int b = e >> 4, c = e & 15;
        hA[c][b] = q.h[b * 512 + s * 16 + c];
      }
      {
        const int nk = tid >> 4, nf = tid & 15;
        *(float4*)&bsA[nk][nf * 4] =
            *(const float4*)(q.aw2 + (size_t)(s * 16 + nk) * 512 + nt * 64 + nf * 4);
      }
      __syncthreads();
      const int tx = tid & 15, ty = tid >> 4;
      float acc[4][4] = {};
#pragma unroll
      for (int k = 0; k < 16; ++k) {
        float4 bv = *(const float4*)&bsA[k][tx * 4];
        float a0 = hA[k][ty * 4 + 0], a1 = hA[k][ty * 4 + 1];
        float a2 = hA[k][ty * 4 + 2], a3 = hA[k][ty * 4 + 3];
        acc[0][0] = fmaf(a0, bv.x, acc[0][0]); acc[0][1] = fmaf(a0, bv.y, acc[0][1]);
        acc[0][2] = fmaf(a0, bv.z, acc[0][2]); acc[0][3] = fmaf(a0, bv.w, acc[0][3]);
        acc[1][0] = fmaf(a1, bv.x, acc[1][0]); acc[1][1] = fmaf(a1, bv.y, acc[1][1]);
        acc[1][2] = fmaf(a1, bv.z, acc[1][2]); acc[1][3] = fmaf(a1, bv.w, acc[1][3]);
        acc[2][0] = fmaf(a2, bv.x, acc[2][0]); acc[2][1] = fmaf(a2, bv.y, acc[2][1]);
        acc[2][2] = fmaf(a2, bv.z, acc[2][2]); acc[2][3] = fmaf(a2, bv.w, acc[2][3]);
        acc[3][0] = fmaf(a3, bv.x, acc[3][0]); acc[3][1] = fmaf(a3, bv.y, acc[3][1]);
        acc[3][2] = fmaf(a3, bv.z, acc[3][2]); acc[3][3] = fmaf(a3, bv.w, acc[3][3]);
      }
      float* op = q.Php + (size_t)s * 64 * 512 + (size_t)nt * 64;
#pragma unroll
      for (int i = 0; i < 4; ++i)
        *(float4*)(op + (size_t)(ty * 4 + i) * 512 + tx * 4) =
            make_float4(acc[i][0], acc[i][1], acc[i][2], acc[i][3]);
      __syncthreads();
    }
    __threadfence();
    grid.sync();

    // ---- S2: attention for batch b = bid (blocks 0..63) ----
    if (bid < 64) {
      const int b = bid;
      for (int j = tid; j < 512; j += 256) {
        float a = 0.f;
        if (t > 0) {
          const float* pp = q.Php + (size_t)b * 512 + j;
#pragma unroll 8
          for (int s2 = 0; s2 < 32; ++s2) a += pp[(size_t)s2 * 64 * 512];
        }
        hp[j] = a;
      }
      if (tid >= RREG && tid < 64) sc[tid] = -1e30f;
      __syncthreads();
      const int wv = tid >> 6, lane = tid & 63;
      float vwr[8], hpr[8];
#pragma unroll
      for (int c = 0; c < 8; ++c) { vwr[c] = q.vw[lane + 64 * c]; hpr[c] = hp[lane + 64 * c]; }
      const float* fpb = q.fproj + (size_t)b * RREG * 512;
      for (int r = wv; r < RREG; r += 4) {
        float sacc = 0.f;
#pragma unroll
        for (int c = 0; c < 8; ++c)
          sacc += vwr[c] * ftanh(fpb[r * 512 + lane + 64 * c] + hpr[c]);
#pragma unroll
        for (int d = 32; d > 0; d >>= 1) sacc += __shfl_xor(sacc, d, 64);
        if (lane == 0) sc[r] = sacc;
      }
      __syncthreads();
      if (wv == 0) {
        float v = sc[lane];
        float m = v;
#pragma unroll
        for (int d = 32; d > 0; d >>= 1) m = fmaxf(m, __shfl_xor(m, d, 64));
        float e = (lane < RREG) ? __expf(v - m) : 0.f;
        float ssum = e;
#pragma unroll
        for (int d = 32; d > 0; d >>= 1) ssum += __shfl_xor(ssum, d, 64);
        sc[lane] = e * frcp(ssum);
      }
      __syncthreads();
      const float* fb = q.features + (size_t)b * RREG * 512;
      for (int j = tid; j < 512; j += 256) {
        float a = 0.f;
        for (int r = 0; r < RREG; ++r) a = fmaf(sc[r], fb[r * 512 + j], a);
        q.ctx[b * 512 + j] = a;
      }
    }
    __threadfence();
    grid.sync();

    // ---- S3: gates partials (blocks 0..95 = 48 n-tiles x splitK2) ----
    if (bid < 96) {
      const int n0g = (bid >> 1) * 64, z = bid & 1;
      const bool hh = (n0g >= 1536);
      const float* A = hh ? q.h : q.ctx;
      const float* B = hh ? q.Whh : q.Wc;
      const int ldb = hh ? 512 : 1024;
      const int nb = hh ? (n0g - 1536) : n0g;
      const int tx = tid & 15, ty = tid >> 4;
      float acc[4][4] = {};
      if (!(hh && t == 0)) {
        const int lr = tid >> 3, lf = tid & 7;
        for (int k0 = z * 256; k0 < z * 256 + 256; k0 += 32) {
          {
            float4 v = *(const float4*)(A + (size_t)lr * 512 + k0 + lf * 4);
            asg[lf * 4 + 0][lr] = v.x; asg[lf * 4 + 1][lr] = v.y;
            asg[lf * 4 + 2][lr] = v.z; asg[lf * 4 + 3][lr] = v.w;
            float4 w = *(const float4*)(A + (size_t)(lr + 32) * 512 + k0 + lf * 4);
            asg[lf * 4 + 0][lr + 32] = w.x; asg[lf * 4 + 1][lr + 32] = w.y;
            asg[lf * 4 + 2][lr + 32] = w.z; asg[lf * 4 + 3][lr + 32] = w.w;
            float4 u = *(const float4*)(B + (size_t)(nb + lr) * ldb + k0 + lf * 4);
            bsg[lf * 4 + 0][lr] = u.x; bsg[lf * 4 + 1][lr] = u.y;
            bsg[lf * 4 + 2][lr] = u.z; bsg[lf * 4 + 3][lr] = u.w;
            float4 x = *(const float4*)(B + (size_t)(nb + lr + 32) * ldb + k0 + lf * 4);
            bsg[lf * 4 + 0][lr + 32] = x.x; bsg[lf * 4 + 1][lr + 32] = x.y;
            bsg[lf * 4 + 2][lr + 32] = x.z; bsg[lf * 4 + 3][lr + 32] = x.w;
          }
          __syncthreads();
#pragma unroll
          for (int k = 0; k < 32; ++k) {
            float4 av = *(const float4*)&asg[k][ty * 4];
            float4 bv = *(const float4*)&bsg[k][tx * 4];
            float aa[4] = {av.x, av.y, av.z, av.w};
            float bb[4] = {bv.x, bv.y, bv.z, bv.w};
#pragma unroll
            for (int i = 0; i < 4; ++i)
#pragma unroll
              for (int jj = 0; jj < 4; ++jj)
                acc[i][jj] = fmaf(aa[i], bb[jj], acc[i][jj]);
          }
          __syncthreads();
        }
      }
      float* Cp = q.P + (size_t)z * 64 * 3072;
#pragma unroll
      for (int i = 0; i < 4; ++i)
        *(float4*)(Cp + (size_t)(ty * 4 + i) * 3072 + n0g + tx * 4) =
            make_float4(acc[i][0], acc[i][1], acc[i][2], acc[i][3]);
    }
    __threadfence();
    grid.sync();
  }
  if (bid < 32) S0(TSTEPS);   // final: h_32 -> hall[:,31]
}

extern "C" void kernel_launch(void* const* d_in, const int* in_sizes, int n_in,
                              void* d_out, int out_size, void* d_ws, size_t ws_size,
                              hipStream_t stream)
{
  const float* features = (const float*)d_in[0];
  const int*   captions = (const int*)d_in[1];
  const float* embed    = (const float*)d_in[2];
  const float* attn_W   = (const float*)d_in[3];
  const float* attn_b   = (const float*)d_in[4];
  const float* v_w      = (const float*)d_in[5];
  const float* W_ih     = (const float*)d_in[6];
  const float* W_hh     = (const float*)d_in[7];
  const float* b_ih     = (const float*)d_in[8];
  const float* b_hh     = (const float*)d_in[9];
  const float* fc_W     = (const float*)d_in[10];
  const float* fc_b     = (const float*)d_in[11];
  float* out = (float*)d_out;

  float* ws = (float*)d_ws;
  float* gxx   = ws; ws += (size_t)2048 * 1536;
  float* fproj = ws; ws += (size_t)3136 * 512;
  float* hbuf  = ws; ws += 64 * 512;
  float* ctxb  = ws; ws += 64 * 512;
  float* P     = ws; ws += (size_t)2 * 64 * 3072;
  float* Php   = ws; ws += (size_t)32 * 64 * 512;
  float* hall  = ws; ws += (size_t)2048 * 512;

  // prologue
  {
    GemmP p1{embed, W_ih, b_ih, nullptr, gxx, 2048, 1536, 512, 512, 1024, 0, 1536, captions};
    GemmP p0{features, attn_W, attn_b, nullptr, fproj, 3136, 512, 512, 512, 512, 0, 512, nullptr};
    k_prologue<<<dim3(12, 25, 2), 256, 0, stream>>>(p1, p0);
  }

  // persistent cooperative recurrence (checked) with multi-kernel fallback
  {
    LoopP lp{gxx, b_hh, hbuf, hall, Php, P, ctxb,
             fproj, features, v_w, attn_W + (size_t)EDIM * HDIM,
             W_ih + EDIM, W_hh};
    void* kargs[] = {(void*)&lp};
    hipError_t cerr = hipLaunchCooperativeKernel((const void*)k_loop2, dim3(256), dim3(256),
                                                 kargs, 0, stream);
    if (cerr != hipSuccess) {
      (void)hipGetLastError();   // clear error state; take the proven multi-kernel path
      for (int t = 0; t < TSTEPS; ++t) {
        k_front<<<64, 512, 0, stream>>>(P, gxx, b_hh, hbuf, hall, fproj, features,
                                        v_w, attn_W + (size_t)EDIM * HDIM, ctxb, t);
        GateP g{ctxb, (t == 0) ? nullptr : hbuf, W_ih + EDIM, W_hh, P};
        k_gates<<<dim3(48, 1, 2), 256, 0, stream>>>(g);
      }
      k_front<<<64, 512, 0, stream>>>(P, gxx, b_hh, hbuf, hall, fproj, features,
                                      v_w, attn_W + (size_t)EDIM * HDIM, ctxb, TSTEPS);
    }
  }

  // vocab projection: out = hall @ fc_W + fc_b  (2048 x 10000 x 512)
  {
    GemmP p{hall, fc_W, fc_b, nullptr, out, 2048, 10000, 512, 512, 10000, 0, 10000, nullptr};
    gemm_k<false, false><<<dim3(79, 16), 256, 0, stream>>>(p);
  }
}

// Round 7
// 5752.014 us; speedup vs baseline: 1.4466x; 1.4466x over previous
//
#include <hip/hip_runtime.h>
#include <hip/hip_cooperative_groups.h>
#include <math.h>

#define TSTEPS 32
#define CAPL 33
#define EDIM 512
#define HDIM 512
#define VOCAB 10000
#define BATCH 64
#define RREG 49
#define NBLK 256

// ---------- fast transcendentals ----------
__device__ __forceinline__ float frcp(float x) { return __builtin_amdgcn_rcpf(x); }
__device__ __forceinline__ float ftanh(float x) {
  float e = __expf(2.f * x);            // saturates correctly at +/-inf
  return 1.f - 2.f * frcp(e + 1.f);
}
__device__ __forceinline__ float fsig(float x) { return frcp(1.f + __expf(-x)); }

// ---------- one-shot global barrier (slot idx used exactly once per launch) ----------
// Prologue zeroes the slots each launch. All NBLK blocks must call with the same idx
// sequence (calls are outside any divergent guards). Device-scope atomics bypass L1;
// trailing __threadfence() invalidates L1 so post-barrier reads see other CUs' writes.
__device__ __forceinline__ void gbar(int* bar, int idx) {
  __syncthreads();
  if (threadIdx.x == 0) {
    __threadfence();                      // release: drain my global writes
    int* p = bar + idx * 16;              // 64B stride to avoid false sharing
    __hip_atomic_fetch_add(p, 1, __ATOMIC_RELAXED, __HIP_MEMORY_SCOPE_AGENT);
    while (__hip_atomic_load(p, __ATOMIC_RELAXED, __HIP_MEMORY_SCOPE_AGENT) < NBLK)
      __builtin_amdgcn_s_sleep(1);
  }
  __syncthreads();
  __threadfence();                        // acquire: invalidate L1 before reading
}

// ================= big-tile fp32 GEMM (prologue + vocab projection) =================
struct GemmP {
  const float* A; const float* B; const float* bias; const float* D;
  float* C; int M, N, K, lda, ldb, ldd, ldc;
  const int* caps;
};

template<bool BT, bool GATHER>
__device__ __forceinline__ void gemm_body(GemmP p, int bx, int by)
{
  __shared__ float as[32][132];
  __shared__ float bs[32][132];
  const int tid = threadIdx.x;
  const int m0 = by * 128, n0 = bx * 128;
  const int tx = tid & 15, ty = tid >> 4;
  float acc[8][8];
#pragma unroll
  for (int i = 0; i < 8; ++i)
#pragma unroll
    for (int j = 0; j < 8; ++j) acc[i][j] = 0.f;

  const int lr = tid >> 3, lf = tid & 7;
  const int nf = tid & 31, nk = tid >> 5;

  for (int k0 = 0; k0 < p.K; k0 += 32) {
#pragma unroll
    for (int q = 0; q < 4; ++q) {
      int m = m0 + lr + 32 * q;
      float4 v = make_float4(0.f, 0.f, 0.f, 0.f);
      if (m < p.M) {
        int row = m;
        if (GATHER) row = p.caps[(m >> 5) * CAPL + (m & 31)];
        v = *(const float4*)(p.A + (size_t)row * p.lda + k0 + lf * 4);
      }
      int rr = lr + 32 * q;
      as[lf * 4 + 0][rr] = v.x; as[lf * 4 + 1][rr] = v.y;
      as[lf * 4 + 2][rr] = v.z; as[lf * 4 + 3][rr] = v.w;
    }
    if (BT) {
#pragma unroll
      for (int q = 0; q < 4; ++q) {
        int n = n0 + lr + 32 * q;
        float4 v = make_float4(0.f, 0.f, 0.f, 0.f);
        if (n < p.N) v = *(const float4*)(p.B + (size_t)n * p.ldb + k0 + lf * 4);
        int rr = lr + 32 * q;
        bs[lf * 4 + 0][rr] = v.x; bs[lf * 4 + 1][rr] = v.y;
        bs[lf * 4 + 2][rr] = v.z; bs[lf * 4 + 3][rr] = v.w;
      }
    } else {
#pragma unroll
      for (int q = 0; q < 4; ++q) {
        int k = nk + 8 * q;
        int n = n0 + nf * 4;
        float4 v = make_float4(0.f, 0.f, 0.f, 0.f);
        if (n < p.N) v = *(const float4*)(p.B + (size_t)(k0 + k) * p.ldb + n);
        *(float4*)&bs[k][nf * 4] = v;
      }
    }
    __syncthreads();
#pragma unroll
    for (int k = 0; k < 32; ++k) {
      float4 a0 = *(const float4*)&as[k][ty * 4];
      float4 a1 = *(const float4*)&as[k][ty * 4 + 64];
      float4 b0 = *(const float4*)&bs[k][tx * 4];
      float4 b1 = *(const float4*)&bs[k][tx * 4 + 64];
      float av[8] = {a0.x, a0.y, a0.z, a0.w, a1.x, a1.y, a1.z, a1.w};
      float bv[8] = {b0.x, b0.y, b0.z, b0.w, b1.x, b1.y, b1.z, b1.w};
#pragma unroll
      for (int i = 0; i < 8; ++i)
#pragma unroll
        for (int j = 0; j < 8; ++j)
          acc[i][j] = fmaf(av[i], bv[j], acc[i][j]);
    }
    __syncthreads();
  }
  const bool hb = (p.bias != nullptr);
  const bool hd = (p.D != nullptr);
#pragma unroll
  for (int i = 0; i < 8; ++i) {
    int m = m0 + ty * 4 + (i & 3) + ((i >> 2) * 64);
    if (m >= p.M) continue;
#pragma unroll
    for (int jj = 0; jj < 2; ++jj) {
      int n = n0 + tx * 4 + jj * 64;
      if (n >= p.N) continue;
      float4 r;
      r.x = acc[i][jj * 4 + 0]; r.y = acc[i][jj * 4 + 1];
      r.z = acc[i][jj * 4 + 2]; r.w = acc[i][jj * 4 + 3];
      if (hb) { r.x += p.bias[n]; r.y += p.bias[n + 1]; r.z += p.bias[n + 2]; r.w += p.bias[n + 3]; }
      if (hd) {
        const float4 d = *(const float4*)(p.D + (size_t)m * p.ldd + n);
        r.x += d.x; r.y += d.y; r.z += d.z; r.w += d.w;
      }
      *(float4*)(p.C + (size_t)m * p.ldc + n) = r;
    }
  }
}

template<bool BT, bool GATHER>
__global__ __launch_bounds__(256) void gemm_k(GemmP p) {
  gemm_body<BT, GATHER>(p, blockIdx.x, blockIdx.y);
}

// fused prologue; block (0,0,0) additionally zeroes the barrier slots for this launch
__global__ __launch_bounds__(256) void k_prologue(GemmP pk1, GemmP pk0, int* bar) {
  if (blockIdx.z == 0 && blockIdx.x == 0 && blockIdx.y == 0) {
    for (int i = threadIdx.x; i < 130 * 16; i += 256) bar[i] = 0;
  }
  if (blockIdx.z == 0) {
    if (blockIdx.x < 12 && blockIdx.y < 16) gemm_body<true, true>(pk1, blockIdx.x, blockIdx.y);
  } else {
    if (blockIdx.x < 4 && blockIdx.y < 25) gemm_body<false, false>(pk0, blockIdx.x, blockIdx.y);
  }
}

// ================= FALLBACK path kernels (round-3 verified) =================
struct GateP {
  const float* ctx; const float* h;
  const float* Wc;  const float* Wh;
  float* P;
};

__global__ __launch_bounds__(256) void k_gates(GateP g)
{
  __shared__ float as[32][68];
  __shared__ float bs[32][68];
  const int tid = threadIdx.x;
  const int n0g = blockIdx.x * 64;
  const bool hh = (n0g >= 1536);
  const float* A = hh ? g.h : g.ctx;
  const float* B = hh ? g.Wh : g.Wc;
  const int ldb = hh ? 512 : 1024;
  const int nb = hh ? (n0g - 1536) : n0g;
  const int kbase = blockIdx.z * 256;
  float* C = g.P + (size_t)blockIdx.z * 64 * 3072;

  const int tx = tid & 15, ty = tid >> 4;
  float acc[4][4] = {};
  if (A != nullptr) {
    const int lr = tid >> 3, lf = tid & 7;
    for (int k0 = kbase; k0 < kbase + 256; k0 += 32) {
      {
        float4 v = *(const float4*)(A + (size_t)lr * 512 + k0 + lf * 4);
        as[lf * 4 + 0][lr] = v.x; as[lf * 4 + 1][lr] = v.y;
        as[lf * 4 + 2][lr] = v.z; as[lf * 4 + 3][lr] = v.w;
        float4 w = *(const float4*)(A + (size_t)(lr + 32) * 512 + k0 + lf * 4);
        as[lf * 4 + 0][lr + 32] = w.x; as[lf * 4 + 1][lr + 32] = w.y;
        as[lf * 4 + 2][lr + 32] = w.z; as[lf * 4 + 3][lr + 32] = w.w;
      }
      {
        float4 v = *(const float4*)(B + (size_t)(nb + lr) * ldb + k0 + lf * 4);
        bs[lf * 4 + 0][lr] = v.x; bs[lf * 4 + 1][lr] = v.y;
        bs[lf * 4 + 2][lr] = v.z; bs[lf * 4 + 3][lr] = v.w;
        float4 w = *(const float4*)(B + (size_t)(nb + lr + 32) * ldb + k0 + lf * 4);
        bs[lf * 4 + 0][lr + 32] = w.x; bs[lf * 4 + 1][lr + 32] = w.y;
        bs[lf * 4 + 2][lr + 32] = w.z; bs[lf * 4 + 3][lr + 32] = w.w;
      }
      __syncthreads();
#pragma unroll
      for (int k = 0; k < 32; ++k) {
        float4 a = *(const float4*)&as[k][ty * 4];
        float4 b = *(const float4*)&bs[k][tx * 4];
        float av[4] = {a.x, a.y, a.z, a.w};
        float bv[4] = {b.x, b.y, b.z, b.w};
#pragma unroll
        for (int i = 0; i < 4; ++i)
#pragma unroll
          for (int j = 0; j < 4; ++j)
            acc[i][j] = fmaf(av[i], bv[j], acc[i][j]);
      }
      __syncthreads();
    }
  }
#pragma unroll
  for (int i = 0; i < 4; ++i) {
    float4 r = make_float4(acc[i][0], acc[i][1], acc[i][2], acc[i][3]);
    *(float4*)(C + (size_t)(ty * 4 + i) * 3072 + n0g + tx * 4) = r;
  }
}

__global__ __launch_bounds__(512) void k_front(
    const float* __restrict__ P, const float* __restrict__ gxx,
    const float* __restrict__ bhh, float* __restrict__ h,
    float* __restrict__ hall, const float* __restrict__ fproj,
    const float* __restrict__ features, const float* __restrict__ vw,
    const float* __restrict__ aw2, float* __restrict__ ctx, int t)
{
  __shared__ float hs[512];
  __shared__ float hp[512];
  __shared__ float sc[64];
  const int b = blockIdx.x, j = threadIdx.x;

  if (t > 0) {
    const float* p0 = P + (size_t)b * 3072;
    const float* p1 = P + (size_t)64 * 3072 + (size_t)b * 3072;
    const float* gx = gxx + ((size_t)b * TSTEPS + (t - 1)) * 1536;
    float xr = p0[j]        + p1[j]        + gx[j];
    float xz = p0[512 + j]  + p1[512 + j]  + gx[512 + j];
    float xn = p0[1024 + j] + p1[1024 + j] + gx[1024 + j];
    float hr = p0[1536 + j] + p1[1536 + j] + bhh[j];
    float hz = p0[2048 + j] + p1[2048 + j] + bhh[512 + j];
    float hn = p0[2560 + j] + p1[2560 + j] + bhh[1024 + j];
    float hold = (t == 1) ? 0.f : h[b * 512 + j];
    float r = fsig(xr + hr);
    float z = fsig(xz + hz);
    float n = ftanh(xn + r * hn);
    float hv = (1.f - z) * n + z * hold;
    h[b * 512 + j] = hv;
    hall[((size_t)b * TSTEPS + (t - 1)) * 512 + j] = hv;
    hs[j] = hv;
  } else {
    hs[j] = 0.f;
  }
  if (t == TSTEPS) return;
  if (j >= RREG && j < 64) sc[j] = -1e30f;
  __syncthreads();

  float hpv = 0.f;
  if (t > 0) {
    float a0 = 0.f, a1 = 0.f, a2 = 0.f, a3 = 0.f;
    for (int k = 0; k < 512; k += 4) {
      a0 = fmaf(hs[k + 0], aw2[(size_t)(k + 0) * 512 + j], a0);
      a1 = fmaf(hs[k + 1], aw2[(size_t)(k + 1) * 512 + j], a1);
      a2 = fmaf(hs[k + 2], aw2[(size_t)(k + 2) * 512 + j], a2);
      a3 = fmaf(hs[k + 3], aw2[(size_t)(k + 3) * 512 + j], a3);
    }
    hpv = (a0 + a1) + (a2 + a3);
  }
  hp[j] = hpv;
  __syncthreads();

  const int wv = j >> 6, lane = j & 63;
  float vwr[8], hpr[8];
#pragma unroll
  for (int c = 0; c < 8; ++c) {
    vwr[c] = vw[lane + 64 * c];
    hpr[c] = hp[lane + 64 * c];
  }
  const float* fpb = fproj + (size_t)b * RREG * 512;
  for (int i = 0; i < 7; ++i) {
    int r = wv + 8 * i;
    if (r < RREG) {
      float s = 0.f;
#pragma unroll
      for (int c = 0; c < 8; ++c)
        s += vwr[c] * ftanh(fpb[r * 512 + lane + 64 * c] + hpr[c]);
#pragma unroll
      for (int d = 32; d > 0; d >>= 1) s += __shfl_xor(s, d, 64);
      if (lane == 0) sc[r] = s;
    }
  }
  __syncthreads();
  if (wv == 0) {
    float v = sc[lane];
    float m = v;
#pragma unroll
    for (int d = 32; d > 0; d >>= 1) m = fmaxf(m, __shfl_xor(m, d, 64));
    float e = (lane < RREG) ? __expf(v - m) : 0.f;
    float ssum = e;
#pragma unroll
    for (int d = 32; d > 0; d >>= 1) ssum += __shfl_xor(ssum, d, 64);
    sc[lane] = e * frcp(ssum);
  }
  __syncthreads();
  float a = 0.f;
  const float* fb = features + (size_t)b * RREG * 512;
  for (int r = 0; r < RREG; ++r) a = fmaf(sc[r], fb[r * 512 + j], a);
  ctx[b * 512 + j] = a;
}

// ================= persistent recurrence with custom global barrier =================
// 256 blocks x 256 threads; 4 one-shot barriers per step (slots 0..127).
// S0 (32 blocks): GRU update, h columns sharded 16-wide; single h buffer.
// S1 (256 blocks = 32 s-chunks x 8 n-tiles): Php[s] = h[:,s-chunk] @ aw2[s-chunk, n-tile]
// S2 (64 blocks): sum Php -> hproj; scores; softmax; ctx
// S3 (96 blocks = 48 n-tiles x splitK2): gates partials P
struct LoopP {
  const float* gxx; const float* bhh;
  float* h; float* hall; float* Php; float* P; float* ctx;
  const float* fproj; const float* features; const float* vw;
  const float* aw2; const float* Wc; const float* Whh;
  int* bar;
};

__global__ __launch_bounds__(256, 1) void k_loop2(LoopP q)
{
  __shared__ float hA[16][65];
  __shared__ float bsA[16][68];
  __shared__ float asg[32][68];
  __shared__ float bsg[32][68];
  __shared__ float hp[512];
  __shared__ float sc[64];
  const int bid = blockIdx.x, tid = threadIdx.x;
  int bix = 0;

  // ---- S0: GRU update for h[:, bid*16 .. +16) (blocks 0..31 only) ----
  auto S0 = [&](int t) {
    const int s = bid;
    for (int e = tid; e < 1024; e += 256) {
      const int b = e >> 4, c = e & 15, j = s * 16 + c;
      const float* p0 = q.P + (size_t)b * 3072;
      const float* p1 = q.P + (size_t)(64 + b) * 3072;
      const float* gx = q.gxx + ((size_t)b * TSTEPS + (t - 1)) * 1536;
      float xr = p0[j]        + p1[j]        + gx[j];
      float xz = p0[512 + j]  + p1[512 + j]  + gx[512 + j];
      float xn = p0[1024 + j] + p1[1024 + j] + gx[1024 + j];
      float hr = p0[1536 + j] + p1[1536 + j] + q.bhh[j];
      float hz = p0[2048 + j] + p1[2048 + j] + q.bhh[512 + j];
      float hn = p0[2560 + j] + p1[2560 + j] + q.bhh[1024 + j];
      float hold = (t == 1) ? 0.f : q.h[b * 512 + j];
      float r = fsig(xr + hr), z = fsig(xz + hz);
      float n = ftanh(xn + r * hn);
      float hv = (1.f - z) * n + z * hold;
      q.h[b * 512 + j] = hv;
      q.hall[((size_t)b * TSTEPS + (t - 1)) * 512 + j] = hv;
    }
  };

  for (int t = 0; t < TSTEPS; ++t) {
    if (t > 0 && bid < 32) S0(t);
    gbar(q.bar, bix++);

    // ---- S1: Php[s][:, nt*64..+64) = h-chunk @ aw2-tile ----
    if (t > 0) {
      const int s = bid & 31, nt = bid >> 5;
      for (int e = tid; e < 1024; e += 256) {
        const int b = e >> 4, c = e & 15;
        hA[c][b] = q.h[b * 512 + s * 16 + c];
      }
      {
        const int nk = tid >> 4, nf = tid & 15;
        *(float4*)&bsA[nk][nf * 4] =
            *(const float4*)(q.aw2 + (size_t)(s * 16 + nk) * 512 + nt * 64 + nf * 4);
      }
      __syncthreads();
      const int tx = tid & 15, ty = tid >> 4;
      float acc[4][4] = {};
#pragma unroll
      for (int k = 0; k < 16; ++k) {
        float4 bv = *(const float4*)&bsA[k][tx * 4];
        float a0 = hA[k][ty * 4 + 0], a1 = hA[k][ty * 4 + 1];
        float a2 = hA[k][ty * 4 + 2], a3 = hA[k][ty * 4 + 3];
        acc[0][0] = fmaf(a0, bv.x, acc[0][0]); acc[0][1] = fmaf(a0, bv.y, acc[0][1]);
        acc[0][2] = fmaf(a0, bv.z, acc[0][2]); acc[0][3] = fmaf(a0, bv.w, acc[0][3]);
        acc[1][0] = fmaf(a1, bv.x, acc[1][0]); acc[1][1] = fmaf(a1, bv.y, acc[1][1]);
        acc[1][2] = fmaf(a1, bv.z, acc[1][2]); acc[1][3] = fmaf(a1, bv.w, acc[1][3]);
        acc[2][0] = fmaf(a2, bv.x, acc[2][0]); acc[2][1] = fmaf(a2, bv.y, acc[2][1]);
        acc[2][2] = fmaf(a2, bv.z, acc[2][2]); acc[2][3] = fmaf(a2, bv.w, acc[2][3]);
        acc[3][0] = fmaf(a3, bv.x, acc[3][0]); acc[3][1] = fmaf(a3, bv.y, acc[3][1]);
        acc[3][2] = fmaf(a3, bv.z, acc[3][2]); acc[3][3] = fmaf(a3, bv.w, acc[3][3]);
      }
      float* op = q.Php + (size_t)s * 64 * 512 + (size_t)nt * 64;
#pragma unroll
      for (int i = 0; i < 4; ++i)
        *(float4*)(op + (size_t)(ty * 4 + i) * 512 + tx * 4) =
            make_float4(acc[i][0], acc[i][1], acc[i][2], acc[i][3]);
      __syncthreads();
    }
    gbar(q.bar, bix++);

    // ---- S2: attention for batch b = bid (blocks 0..63) ----
    if (bid < 64) {
      const int b = bid;
      for (int j = tid; j < 512; j += 256) {
        float a = 0.f;
        if (t > 0) {
          const float* pp = q.Php + (size_t)b * 512 + j;
#pragma unroll 8
          for (int s2 = 0; s2 < 32; ++s2) a += pp[(size_t)s2 * 64 * 512];
        }
        hp[j] = a;
      }
      if (tid >= RREG && tid < 64) sc[tid] = -1e30f;
      __syncthreads();
      const int wv = tid >> 6, lane = tid & 63;
      float vwr[8], hpr[8];
#pragma unroll
      for (int c = 0; c < 8; ++c) { vwr[c] = q.vw[lane + 64 * c]; hpr[c] = hp[lane + 64 * c]; }
      const float* fpb = q.fproj + (size_t)b * RREG * 512;
      for (int r = wv; r < RREG; r += 4) {
        float sacc = 0.f;
#pragma unroll
        for (int c = 0; c < 8; ++c)
          sacc += vwr[c] * ftanh(fpb[r * 512 + lane + 64 * c] + hpr[c]);
#pragma unroll
        for (int d = 32; d > 0; d >>= 1) sacc += __shfl_xor(sacc, d, 64);
        if (lane == 0) sc[r] = sacc;
      }
      __syncthreads();
      if (wv == 0) {
        float v = sc[lane];
        float m = v;
#pragma unroll
        for (int d = 32; d > 0; d >>= 1) m = fmaxf(m, __shfl_xor(m, d, 64));
        float e = (lane < RREG) ? __expf(v - m) : 0.f;
        float ssum = e;
#pragma unroll
        for (int d = 32; d > 0; d >>= 1) ssum += __shfl_xor(ssum, d, 64);
        sc[lane] = e * frcp(ssum);
      }
      __syncthreads();
      const float* fb = q.features + (size_t)b * RREG * 512;
      for (int j = tid; j < 512; j += 256) {
        float a = 0.f;
        for (int r = 0; r < RREG; ++r) a = fmaf(sc[r], fb[r * 512 + j], a);
        q.ctx[b * 512 + j] = a;
      }
    }
    gbar(q.bar, bix++);

    // ---- S3: gates partials (blocks 0..95 = 48 n-tiles x splitK2) ----
    if (bid < 96) {
      const int n0g = (bid >> 1) * 64, z = bid & 1;
      const bool hh = (n0g >= 1536);
      const float* A = hh ? q.h : q.ctx;
      const float* B = hh ? q.Whh : q.Wc;
      const int ldb = hh ? 512 : 1024;
      const int nb = hh ? (n0g - 1536) : n0g;
      const int tx = tid & 15, ty = tid >> 4;
      float acc[4][4] = {};
      if (!(hh && t == 0)) {
        const int lr = tid >> 3, lf = tid & 7;
        for (int k0 = z * 256; k0 < z * 256 + 256; k0 += 32) {
          {
            float4 v = *(const float4*)(A + (size_t)lr * 512 + k0 + lf * 4);
            asg[lf * 4 + 0][lr] = v.x; asg[lf * 4 + 1][lr] = v.y;
            asg[lf * 4 + 2][lr] = v.z; asg[lf * 4 + 3][lr] = v.w;
            float4 w = *(const float4*)(A + (size_t)(lr + 32) * 512 + k0 + lf * 4);
            asg[lf * 4 + 0][lr + 32] = w.x; asg[lf * 4 + 1][lr + 32] = w.y;
            asg[lf * 4 + 2][lr + 32] = w.z; asg[lf * 4 + 3][lr + 32] = w.w;
            float4 u = *(const float4*)(B + (size_t)(nb + lr) * ldb + k0 + lf * 4);
            bsg[lf * 4 + 0][lr] = u.x; bsg[lf * 4 + 1][lr] = u.y;
            bsg[lf * 4 + 2][lr] = u.z; bsg[lf * 4 + 3][lr] = u.w;
            float4 x = *(const float4*)(B + (size_t)(nb + lr + 32) * ldb + k0 + lf * 4);
            bsg[lf * 4 + 0][lr + 32] = x.x; bsg[lf * 4 + 1][lr + 32] = x.y;
            bsg[lf * 4 + 2][lr + 32] = x.z; bsg[lf * 4 + 3][lr + 32] = x.w;
          }
          __syncthreads();
#pragma unroll
          for (int k = 0; k < 32; ++k) {
            float4 av = *(const float4*)&asg[k][ty * 4];
            float4 bv = *(const float4*)&bsg[k][tx * 4];
            float aa[4] = {av.x, av.y, av.z, av.w};
            float bb[4] = {bv.x, bv.y, bv.z, bv.w};
#pragma unroll
            for (int i = 0; i < 4; ++i)
#pragma unroll
              for (int jj = 0; jj < 4; ++jj)
                acc[i][jj] = fmaf(aa[i], bb[jj], acc[i][jj]);
          }
          __syncthreads();
        }
      }
      float* Cp = q.P + (size_t)z * 64 * 3072;
#pragma unroll
      for (int i = 0; i < 4; ++i)
        *(float4*)(Cp + (size_t)(ty * 4 + i) * 3072 + n0g + tx * 4) =
            make_float4(acc[i][0], acc[i][1], acc[i][2], acc[i][3]);
    }
    gbar(q.bar, bix++);
  }
  if (bid < 32) S0(TSTEPS);   // final: h_32 -> hall[:,31]
}

extern "C" void kernel_launch(void* const* d_in, const int* in_sizes, int n_in,
                              void* d_out, int out_size, void* d_ws, size_t ws_size,
                              hipStream_t stream)
{
  const float* features = (const float*)d_in[0];
  const int*   captions = (const int*)d_in[1];
  const float* embed    = (const float*)d_in[2];
  const float* attn_W   = (const float*)d_in[3];
  const float* attn_b   = (const float*)d_in[4];
  const float* v_w      = (const float*)d_in[5];
  const float* W_ih     = (const float*)d_in[6];
  const float* W_hh     = (const float*)d_in[7];
  const float* b_ih     = (const float*)d_in[8];
  const float* b_hh     = (const float*)d_in[9];
  const float* fc_W     = (const float*)d_in[10];
  const float* fc_b     = (const float*)d_in[11];
  float* out = (float*)d_out;

  float* ws = (float*)d_ws;
  float* gxx   = ws; ws += (size_t)2048 * 1536;
  float* fproj = ws; ws += (size_t)3136 * 512;
  float* hbuf  = ws; ws += 64 * 512;
  float* ctxb  = ws; ws += 64 * 512;
  float* P     = ws; ws += (size_t)2 * 64 * 3072;
  float* Php   = ws; ws += (size_t)32 * 64 * 512;
  float* hall  = ws; ws += (size_t)2048 * 512;
  int*   bar   = (int*)ws; ws += 130 * 16;

  // prologue (also zeroes barrier slots for this launch)
  {
    GemmP p1{embed, W_ih, b_ih, nullptr, gxx, 2048, 1536, 512, 512, 1024, 0, 1536, captions};
    GemmP p0{features, attn_W, attn_b, nullptr, fproj, 3136, 512, 512, 512, 512, 0, 512, nullptr};
    k_prologue<<<dim3(12, 25, 2), 256, 0, stream>>>(p1, p0, bar);
  }

  // persistent recurrence; cooperative launch guarantees co-residency for the
  // custom barrier. Checked, with the round-3 multi-kernel fallback.
  {
    LoopP lp{gxx, b_hh, hbuf, hall, Php, P, ctxb,
             fproj, features, v_w, attn_W + (size_t)EDIM * HDIM,
             W_ih + EDIM, W_hh, bar};
    void* kargs[] = {(void*)&lp};
    hipError_t cerr = hipLaunchCooperativeKernel((const void*)k_loop2, dim3(NBLK), dim3(256),
                                                 kargs, 0, stream);
    if (cerr != hipSuccess) {
      (void)hipGetLastError();   // clear error state; take the proven multi-kernel path
      for (int t = 0; t < TSTEPS; ++t) {
        k_front<<<64, 512, 0, stream>>>(P, gxx, b_hh, hbuf, hall, fproj, features,
                                        v_w, attn_W + (size_t)EDIM * HDIM, ctxb, t);
        GateP g{ctxb, (t == 0) ? nullptr : hbuf, W_ih + EDIM, W_hh, P};
        k_gates<<<dim3(48, 1, 2), 256, 0, stream>>>(g);
      }
      k_front<<<64, 512, 0, stream>>>(P, gxx, b_hh, hbuf, hall, fproj, features,
                                      v_w, attn_W + (size_t)EDIM * HDIM, ctxb, TSTEPS);
    }
  }

  // vocab projection: out = hall @ fc_W + fc_b  (2048 x 10000 x 512)
  {
    GemmP p{hall, fc_W, fc_b, nullptr, out, 2048, 10000, 512, 512, 10000, 0, 10000, nullptr};
    gemm_k<false, false><<<dim3(79, 16), 256, 0, stream>>>(p);
  }
}

// Round 8
// 2416.000 us; speedup vs baseline: 3.4440x; 2.3808x over previous
//
#include <hip/hip_runtime.h>
#include <math.h>

#define TSTEPS 32
#define CAPL 33
#define EDIM 512
#define HDIM 512
#define VOCAB 10000
#define BATCH 64
#define RREG 49
#define NBLK 256
#define SLOT 512           // ints per one-shot barrier slot (32 x 64B lines)
#define NSLOTS 130

// ---------- fast transcendentals ----------
__device__ __forceinline__ float frcp(float x) { return __builtin_amdgcn_rcpf(x); }
__device__ __forceinline__ float ftanh(float x) {
  float e = __expf(2.f * x);
  return 1.f - 2.f * frcp(e + 1.f);
}
__device__ __forceinline__ float fsig(float x) { return frcp(1.f + __expf(-x)); }

// ---------- cross-XCD coherent IO (bypasses non-coherent L1/L2; no fences needed) ----------
__device__ __forceinline__ float4 ld_sc4(const float* p) {
  union { float4 f; unsigned long long u[2]; } r;
  r.u[0] = __hip_atomic_load((const unsigned long long*)p, __ATOMIC_RELAXED, __HIP_MEMORY_SCOPE_AGENT);
  r.u[1] = __hip_atomic_load((const unsigned long long*)p + 1, __ATOMIC_RELAXED, __HIP_MEMORY_SCOPE_AGENT);
  return r.f;
}
__device__ __forceinline__ void st_sc4(float* p, float4 v) {
  union { float4 f; unsigned long long u[2]; } r; r.f = v;
  __hip_atomic_store((unsigned long long*)p, r.u[0], __ATOMIC_RELAXED, __HIP_MEMORY_SCOPE_AGENT);
  __hip_atomic_store((unsigned long long*)p + 1, r.u[1], __ATOMIC_RELAXED, __HIP_MEMORY_SCOPE_AGENT);
}

// ---------- fence-free tree barrier (one-shot slot per call; prologue zeroes slots) ----------
// All waves drain vmcnt (sc-stores ack'd at coherence point) -> block sync -> thread0:
// group arrive counter (8 groups x 32) -> root -> per-group release flags. All relaxed.
__device__ __forceinline__ void gbar(int* bar, int idx) {
  asm volatile("s_waitcnt vmcnt(0)" ::: "memory");
  __syncthreads();
  if (threadIdx.x == 0) {
    int* base = bar + idx * SLOT;
    const int g = blockIdx.x >> 5;
    int* garr = base + g * 16;
    int* root = base + 8 * 16;
    int* grel = base + (16 + g) * 16;
    bool rel = false;
    int a = __hip_atomic_fetch_add(garr, 1, __ATOMIC_RELAXED, __HIP_MEMORY_SCOPE_AGENT);
    if (a == 31) {
      int r = __hip_atomic_fetch_add(root, 1, __ATOMIC_RELAXED, __HIP_MEMORY_SCOPE_AGENT);
      rel = (r == 7);
    }
    if (rel) {
#pragma unroll
      for (int gg = 0; gg < 8; ++gg)
        __hip_atomic_store(base + (16 + gg) * 16, 1, __ATOMIC_RELAXED, __HIP_MEMORY_SCOPE_AGENT);
    } else {
      while (__hip_atomic_load(grel, __ATOMIC_RELAXED, __HIP_MEMORY_SCOPE_AGENT) == 0)
        __builtin_amdgcn_s_sleep(1);
    }
  }
  __syncthreads();
}

// ================= big-tile fp32 GEMM (prologue + vocab projection) =================
struct GemmP {
  const float* A; const float* B; const float* bias; const float* D;
  float* C; int M, N, K, lda, ldb, ldd, ldc;
  const int* caps;
};

template<bool BT, bool GATHER>
__device__ __forceinline__ void gemm_body(GemmP p, int bx, int by)
{
  __shared__ float as[32][132];
  __shared__ float bs[32][132];
  const int tid = threadIdx.x;
  const int m0 = by * 128, n0 = bx * 128;
  const int tx = tid & 15, ty = tid >> 4;
  float acc[8][8];
#pragma unroll
  for (int i = 0; i < 8; ++i)
#pragma unroll
    for (int j = 0; j < 8; ++j) acc[i][j] = 0.f;

  const int lr = tid >> 3, lf = tid & 7;
  const int nf = tid & 31, nk = tid >> 5;

  for (int k0 = 0; k0 < p.K; k0 += 32) {
#pragma unroll
    for (int q = 0; q < 4; ++q) {
      int m = m0 + lr + 32 * q;
      float4 v = make_float4(0.f, 0.f, 0.f, 0.f);
      if (m < p.M) {
        int row = m;
        if (GATHER) row = p.caps[(m >> 5) * CAPL + (m & 31)];
        v = *(const float4*)(p.A + (size_t)row * p.lda + k0 + lf * 4);
      }
      int rr = lr + 32 * q;
      as[lf * 4 + 0][rr] = v.x; as[lf * 4 + 1][rr] = v.y;
      as[lf * 4 + 2][rr] = v.z; as[lf * 4 + 3][rr] = v.w;
    }
    if (BT) {
#pragma unroll
      for (int q = 0; q < 4; ++q) {
        int n = n0 + lr + 32 * q;
        float4 v = make_float4(0.f, 0.f, 0.f, 0.f);
        if (n < p.N) v = *(const float4*)(p.B + (size_t)n * p.ldb + k0 + lf * 4);
        int rr = lr + 32 * q;
        bs[lf * 4 + 0][rr] = v.x; bs[lf * 4 + 1][rr] = v.y;
        bs[lf * 4 + 2][rr] = v.z; bs[lf * 4 + 3][rr] = v.w;
      }
    } else {
#pragma unroll
      for (int q = 0; q < 4; ++q) {
        int k = nk + 8 * q;
        int n = n0 + nf * 4;
        float4 v = make_float4(0.f, 0.f, 0.f, 0.f);
        if (n < p.N) v = *(const float4*)(p.B + (size_t)(k0 + k) * p.ldb + n);
        *(float4*)&bs[k][nf * 4] = v;
      }
    }
    __syncthreads();
#pragma unroll
    for (int k = 0; k < 32; ++k) {
      float4 a0 = *(const float4*)&as[k][ty * 4];
      float4 a1 = *(const float4*)&as[k][ty * 4 + 64];
      float4 b0 = *(const float4*)&bs[k][tx * 4];
      float4 b1 = *(const float4*)&bs[k][tx * 4 + 64];
      float av[8] = {a0.x, a0.y, a0.z, a0.w, a1.x, a1.y, a1.z, a1.w};
      float bv[8] = {b0.x, b0.y, b0.z, b0.w, b1.x, b1.y, b1.z, b1.w};
#pragma unroll
      for (int i = 0; i < 8; ++i)
#pragma unroll
        for (int j = 0; j < 8; ++j)
          acc[i][j] = fmaf(av[i], bv[j], acc[i][j]);
    }
    __syncthreads();
  }
  const bool hb = (p.bias != nullptr);
  const bool hd = (p.D != nullptr);
#pragma unroll
  for (int i = 0; i < 8; ++i) {
    int m = m0 + ty * 4 + (i & 3) + ((i >> 2) * 64);
    if (m >= p.M) continue;
#pragma unroll
    for (int jj = 0; jj < 2; ++jj) {
      int n = n0 + tx * 4 + jj * 64;
      if (n >= p.N) continue;
      float4 r;
      r.x = acc[i][jj * 4 + 0]; r.y = acc[i][jj * 4 + 1];
      r.z = acc[i][jj * 4 + 2]; r.w = acc[i][jj * 4 + 3];
      if (hb) { r.x += p.bias[n]; r.y += p.bias[n + 1]; r.z += p.bias[n + 2]; r.w += p.bias[n + 3]; }
      if (hd) {
        const float4 d = *(const float4*)(p.D + (size_t)m * p.ldd + n);
        r.x += d.x; r.y += d.y; r.z += d.z; r.w += d.w;
      }
      *(float4*)(p.C + (size_t)m * p.ldc + n) = r;
    }
  }
}

template<bool BT, bool GATHER>
__global__ __launch_bounds__(256) void gemm_k(GemmP p) {
  gemm_body<BT, GATHER>(p, blockIdx.x, blockIdx.y);
}

__global__ __launch_bounds__(256) void k_prologue(GemmP pk1, GemmP pk0, int* bar) {
  if (blockIdx.z == 0 && blockIdx.x == 0 && blockIdx.y == 0) {
    for (int i = threadIdx.x; i < NSLOTS * SLOT; i += 256) bar[i] = 0;
  }
  if (blockIdx.z == 0) {
    if (blockIdx.x < 12 && blockIdx.y < 16) gemm_body<true, true>(pk1, blockIdx.x, blockIdx.y);
  } else {
    if (blockIdx.x < 4 && blockIdx.y < 25) gemm_body<false, false>(pk0, blockIdx.x, blockIdx.y);
  }
}

// ================= FALLBACK path kernels (round-3 verified) =================
struct GateP {
  const float* ctx; const float* h;
  const float* Wc;  const float* Wh;
  float* P;
};

__global__ __launch_bounds__(256) void k_gates(GateP g)
{
  __shared__ float as[32][68];
  __shared__ float bs[32][68];
  const int tid = threadIdx.x;
  const int n0g = blockIdx.x * 64;
  const bool hh = (n0g >= 1536);
  const float* A = hh ? g.h : g.ctx;
  const float* B = hh ? g.Wh : g.Wc;
  const int ldb = hh ? 512 : 1024;
  const int nb = hh ? (n0g - 1536) : n0g;
  const int kbase = blockIdx.z * 256;
  float* C = g.P + (size_t)blockIdx.z * 64 * 3072;

  const int tx = tid & 15, ty = tid >> 4;
  float acc[4][4] = {};
  if (A != nullptr) {
    const int lr = tid >> 3, lf = tid & 7;
    for (int k0 = kbase; k0 < kbase + 256; k0 += 32) {
      {
        float4 v = *(const float4*)(A + (size_t)lr * 512 + k0 + lf * 4);
        as[lf * 4 + 0][lr] = v.x; as[lf * 4 + 1][lr] = v.y;
        as[lf * 4 + 2][lr] = v.z; as[lf * 4 + 3][lr] = v.w;
        float4 w = *(const float4*)(A + (size_t)(lr + 32) * 512 + k0 + lf * 4);
        as[lf * 4 + 0][lr + 32] = w.x; as[lf * 4 + 1][lr + 32] = w.y;
        as[lf * 4 + 2][lr + 32] = w.z; as[lf * 4 + 3][lr + 32] = w.w;
      }
      {
        float4 v = *(const float4*)(B + (size_t)(nb + lr) * ldb + k0 + lf * 4);
        bs[lf * 4 + 0][lr] = v.x; bs[lf * 4 + 1][lr] = v.y;
        bs[lf * 4 + 2][lr] = v.z; bs[lf * 4 + 3][lr] = v.w;
        float4 w = *(const float4*)(B + (size_t)(nb + lr + 32) * ldb + k0 + lf * 4);
        bs[lf * 4 + 0][lr + 32] = w.x; bs[lf * 4 + 1][lr + 32] = w.y;
        bs[lf * 4 + 2][lr + 32] = w.z; bs[lf * 4 + 3][lr + 32] = w.w;
      }
      __syncthreads();
#pragma unroll
      for (int k = 0; k < 32; ++k) {
        float4 a = *(const float4*)&as[k][ty * 4];
        float4 b = *(const float4*)&bs[k][tx * 4];
        float av[4] = {a.x, a.y, a.z, a.w};
        float bv[4] = {b.x, b.y, b.z, b.w};
#pragma unroll
        for (int i = 0; i < 4; ++i)
#pragma unroll
          for (int j = 0; j < 4; ++j)
            acc[i][j] = fmaf(av[i], bv[j], acc[i][j]);
      }
      __syncthreads();
    }
  }
#pragma unroll
  for (int i = 0; i < 4; ++i) {
    float4 r = make_float4(acc[i][0], acc[i][1], acc[i][2], acc[i][3]);
    *(float4*)(C + (size_t)(ty * 4 + i) * 3072 + n0g + tx * 4) = r;
  }
}

__global__ __launch_bounds__(512) void k_front(
    const float* __restrict__ P, const float* __restrict__ gxx,
    const float* __restrict__ bhh, float* __restrict__ h,
    float* __restrict__ hall, const float* __restrict__ fproj,
    const float* __restrict__ features, const float* __restrict__ vw,
    const float* __restrict__ aw2, float* __restrict__ ctx, int t)
{
  __shared__ float hs[512];
  __shared__ float hp[512];
  __shared__ float sc[64];
  const int b = blockIdx.x, j = threadIdx.x;

  if (t > 0) {
    const float* p0 = P + (size_t)b * 3072;
    const float* p1 = P + (size_t)64 * 3072 + (size_t)b * 3072;
    const float* gx = gxx + ((size_t)b * TSTEPS + (t - 1)) * 1536;
    float xr = p0[j]        + p1[j]        + gx[j];
    float xz = p0[512 + j]  + p1[512 + j]  + gx[512 + j];
    float xn = p0[1024 + j] + p1[1024 + j] + gx[1024 + j];
    float hr = p0[1536 + j] + p1[1536 + j] + bhh[j];
    float hz = p0[2048 + j] + p1[2048 + j] + bhh[512 + j];
    float hn = p0[2560 + j] + p1[2560 + j] + bhh[1024 + j];
    float hold = (t == 1) ? 0.f : h[b * 512 + j];
    float r = fsig(xr + hr);
    float z = fsig(xz + hz);
    float n = ftanh(xn + r * hn);
    float hv = (1.f - z) * n + z * hold;
    h[b * 512 + j] = hv;
    hall[((size_t)b * TSTEPS + (t - 1)) * 512 + j] = hv;
    hs[j] = hv;
  } else {
    hs[j] = 0.f;
  }
  if (t == TSTEPS) return;
  if (j >= RREG && j < 64) sc[j] = -1e30f;
  __syncthreads();

  float hpv = 0.f;
  if (t > 0) {
    float a0 = 0.f, a1 = 0.f, a2 = 0.f, a3 = 0.f;
    for (int k = 0; k < 512; k += 4) {
      a0 = fmaf(hs[k + 0], aw2[(size_t)(k + 0) * 512 + j], a0);
      a1 = fmaf(hs[k + 1], aw2[(size_t)(k + 1) * 512 + j], a1);
      a2 = fmaf(hs[k + 2], aw2[(size_t)(k + 2) * 512 + j], a2);
      a3 = fmaf(hs[k + 3], aw2[(size_t)(k + 3) * 512 + j], a3);
    }
    hpv = (a0 + a1) + (a2 + a3);
  }
  hp[j] = hpv;
  __syncthreads();

  const int wv = j >> 6, lane = j & 63;
  float vwr[8], hpr[8];
#pragma unroll
  for (int c = 0; c < 8; ++c) {
    vwr[c] = vw[lane + 64 * c];
    hpr[c] = hp[lane + 64 * c];
  }
  const float* fpb = fproj + (size_t)b * RREG * 512;
  for (int i = 0; i < 7; ++i) {
    int r = wv + 8 * i;
    if (r < RREG) {
      float s = 0.f;
#pragma unroll
      for (int c = 0; c < 8; ++c)
        s += vwr[c] * ftanh(fpb[r * 512 + lane + 64 * c] + hpr[c]);
#pragma unroll
      for (int d = 32; d > 0; d >>= 1) s += __shfl_xor(s, d, 64);
      if (lane == 0) sc[r] = s;
    }
  }
  __syncthreads();
  if (wv == 0) {
    float v = sc[lane];
    float m = v;
#pragma unroll
    for (int d = 32; d > 0; d >>= 1) m = fmaxf(m, __shfl_xor(m, d, 64));
    float e = (lane < RREG) ? __expf(v - m) : 0.f;
    float ssum = e;
#pragma unroll
    for (int d = 32; d > 0; d >>= 1) ssum += __shfl_xor(ssum, d, 64);
    sc[lane] = e * frcp(ssum);
  }
  __syncthreads();
  float a = 0.f;
  const float* fb = features + (size_t)b * RREG * 512;
  for (int r = 0; r < RREG; ++r) a = fmaf(sc[r], fb[r * 512 + j], a);
  ctx[b * 512 + j] = a;
}

// ================= persistent recurrence, fence-free =================
// Same phase structure/sharding as round 7 (verified); cross-phase buffers
// (h, Php, ctx, P) via sc0sc1 coherent IO; weights via normal cached loads
// (stay L2-hot across steps); tree barrier, no __threadfence anywhere.
struct LoopP {
  const float* gxx; const float* bhh;
  float* h; float* hall; float* Php; float* P; float* ctx;
  const float* fproj; const float* features; const float* vw;
  const float* aw2; const float* Wc; const float* Whh;
  int* bar;
};

__global__ __launch_bounds__(256, 1) void k_loop2(LoopP q)
{
  __shared__ float hA[16][65];
  __shared__ float bsA[16][68];
  __shared__ float asg[32][68];
  __shared__ float bsg[32][68];
  __shared__ float hp[512];
  __shared__ float sc[64];
  const int bid = blockIdx.x, tid = threadIdx.x;
  int bix = 0;

  // ---- S0: GRU update for h[:, bid*16 .. +16) (blocks 0..31), float4 per thread ----
  auto S0 = [&](int t) {
    const int s = bid;
    const int b = tid >> 2, j = s * 16 + (tid & 3) * 4;
    const float* p0 = q.P + (size_t)b * 3072 + j;
    const float* p1 = q.P + (size_t)(64 + b) * 3072 + j;
    const float* gx = q.gxx + ((size_t)b * TSTEPS + (t - 1)) * 1536 + j;
    float4 xr = ld_sc4(p0);        float4 xz = ld_sc4(p0 + 512);  float4 xn = ld_sc4(p0 + 1024);
    float4 hr = ld_sc4(p0 + 1536); float4 hz = ld_sc4(p0 + 2048); float4 hn = ld_sc4(p0 + 2560);
    {
      float4 v;
      v = ld_sc4(p1);        xr.x += v.x; xr.y += v.y; xr.z += v.z; xr.w += v.w;
      v = ld_sc4(p1 + 512);  xz.x += v.x; xz.y += v.y; xz.z += v.z; xz.w += v.w;
      v = ld_sc4(p1 + 1024); xn.x += v.x; xn.y += v.y; xn.z += v.z; xn.w += v.w;
      v = ld_sc4(p1 + 1536); hr.x += v.x; hr.y += v.y; hr.z += v.z; hr.w += v.w;
      v = ld_sc4(p1 + 2048); hz.x += v.x; hz.y += v.y; hz.z += v.z; hz.w += v.w;
      v = ld_sc4(p1 + 2560); hn.x += v.x; hn.y += v.y; hn.z += v.z; hn.w += v.w;
    }
    float4 g0 = *(const float4*)(gx);
    float4 g1 = *(const float4*)(gx + 512);
    float4 g2 = *(const float4*)(gx + 1024);
    float4 b0 = *(const float4*)(q.bhh + j);
    float4 b1 = *(const float4*)(q.bhh + 512 + j);
    float4 b2 = *(const float4*)(q.bhh + 1024 + j);
    float4 hold = make_float4(0.f, 0.f, 0.f, 0.f);
    if (t > 1) hold = ld_sc4(q.h + b * 512 + j);
    float xrl[4] = {xr.x + g0.x, xr.y + g0.y, xr.z + g0.z, xr.w + g0.w};
    float xzl[4] = {xz.x + g1.x, xz.y + g1.y, xz.z + g1.z, xz.w + g1.w};
    float xnl[4] = {xn.x + g2.x, xn.y + g2.y, xn.z + g2.z, xn.w + g2.w};
    float hrl[4] = {hr.x + b0.x, hr.y + b0.y, hr.z + b0.z, hr.w + b0.w};
    float hzl[4] = {hz.x + b1.x, hz.y + b1.y, hz.z + b1.z, hz.w + b1.w};
    float hnl[4] = {hn.x + b2.x, hn.y + b2.y, hn.z + b2.z, hn.w + b2.w};
    float hol[4] = {hold.x, hold.y, hold.z, hold.w};
    float hv[4];
#pragma unroll
    for (int i = 0; i < 4; ++i) {
      float r = fsig(xrl[i] + hrl[i]);
      float z = fsig(xzl[i] + hzl[i]);
      float n = ftanh(xnl[i] + r * hnl[i]);
      hv[i] = (1.f - z) * n + z * hol[i];
    }
    float4 out = make_float4(hv[0], hv[1], hv[2], hv[3]);
    st_sc4(q.h + b * 512 + j, out);
    *(float4*)(q.hall + ((size_t)b * TSTEPS + (t - 1)) * 512 + j) = out;
  };

  for (int t = 0; t < TSTEPS; ++t) {
    if (t > 0 && bid < 32) S0(t);
    gbar(q.bar, bix++);

    // ---- S1: Php[s][:, nt*64..+64) = h-chunk @ aw2-tile ----
    if (t > 0) {
      const int s = bid & 31, nt = bid >> 5;
      {
        const int b = tid >> 2, c0 = (tid & 3) * 4;
        float4 v = ld_sc4(q.h + b * 512 + s * 16 + c0);
        hA[c0 + 0][b] = v.x; hA[c0 + 1][b] = v.y;
        hA[c0 + 2][b] = v.z; hA[c0 + 3][b] = v.w;
      }
      {
        const int nk = tid >> 4, nf = tid & 15;
        *(float4*)&bsA[nk][nf * 4] =
            *(const float4*)(q.aw2 + (size_t)(s * 16 + nk) * 512 + nt * 64 + nf * 4);
      }
      __syncthreads();
      const int tx = tid & 15, ty = tid >> 4;
      float acc[4][4] = {};
#pragma unroll
      for (int k = 0; k < 16; ++k) {
        float4 bv = *(const float4*)&bsA[k][tx * 4];
        float a0 = hA[k][ty * 4 + 0], a1 = hA[k][ty * 4 + 1];
        float a2 = hA[k][ty * 4 + 2], a3 = hA[k][ty * 4 + 3];
        acc[0][0] = fmaf(a0, bv.x, acc[0][0]); acc[0][1] = fmaf(a0, bv.y, acc[0][1]);
        acc[0][2] = fmaf(a0, bv.z, acc[0][2]); acc[0][3] = fmaf(a0, bv.w, acc[0][3]);
        acc[1][0] = fmaf(a1, bv.x, acc[1][0]); acc[1][1] = fmaf(a1, bv.y, acc[1][1]);
        acc[1][2] = fmaf(a1, bv.z, acc[1][2]); acc[1][3] = fmaf(a1, bv.w, acc[1][3]);
        acc[2][0] = fmaf(a2, bv.x, acc[2][0]); acc[2][1] = fmaf(a2, bv.y, acc[2][1]);
        acc[2][2] = fmaf(a2, bv.z, acc[2][2]); acc[2][3] = fmaf(a2, bv.w, acc[2][3]);
        acc[3][0] = fmaf(a3, bv.x, acc[3][0]); acc[3][1] = fmaf(a3, bv.y, acc[3][1]);
        acc[3][2] = fmaf(a3, bv.z, acc[3][2]); acc[3][3] = fmaf(a3, bv.w, acc[3][3]);
      }
      float* op = q.Php + (size_t)s * 64 * 512 + (size_t)nt * 64;
#pragma unroll
      for (int i = 0; i < 4; ++i)
        st_sc4(op + (size_t)((tid >> 4) * 4 + i) * 512 + (tid & 15) * 4,
               make_float4(acc[i][0], acc[i][1], acc[i][2], acc[i][3]));
      __syncthreads();
    }
    gbar(q.bar, bix++);

    // ---- S2: attention for batch b = bid (blocks 0..63) ----
    if (bid < 64) {
      const int b = bid;
      if (tid < 128) {
        const int j0 = tid * 4;
        float4 a = make_float4(0.f, 0.f, 0.f, 0.f);
        if (t > 0) {
          const float* pp = q.Php + (size_t)b * 512 + j0;
#pragma unroll 4
          for (int s2 = 0; s2 < 32; ++s2) {
            float4 v = ld_sc4(pp + (size_t)s2 * 64 * 512);
            a.x += v.x; a.y += v.y; a.z += v.z; a.w += v.w;
          }
        }
        *(float4*)&hp[j0] = a;
      }
      if (tid >= RREG && tid < 64) sc[tid] = -1e30f;
      __syncthreads();
      const int wv = tid >> 6, lane = tid & 63;
      float vwr[8], hpr[8];
#pragma unroll
      for (int c = 0; c < 8; ++c) { vwr[c] = q.vw[lane + 64 * c]; hpr[c] = hp[lane + 64 * c]; }
      const float* fpb = q.fproj + (size_t)b * RREG * 512;
      for (int r = wv; r < RREG; r += 4) {
        float sacc = 0.f;
#pragma unroll
        for (int c = 0; c < 8; ++c)
          sacc += vwr[c] * ftanh(fpb[r * 512 + lane + 64 * c] + hpr[c]);
#pragma unroll
        for (int d = 32; d > 0; d >>= 1) sacc += __shfl_xor(sacc, d, 64);
        if (lane == 0) sc[r] = sacc;
      }
      __syncthreads();
      if (wv == 0) {
        float v = sc[lane];
        float m = v;
#pragma unroll
        for (int d = 32; d > 0; d >>= 1) m = fmaxf(m, __shfl_xor(m, d, 64));
        float e = (lane < RREG) ? __expf(v - m) : 0.f;
        float ssum = e;
#pragma unroll
        for (int d = 32; d > 0; d >>= 1) ssum += __shfl_xor(ssum, d, 64);
        sc[lane] = e * frcp(ssum);
      }
      __syncthreads();
      if (tid < 128) {
        const int j0 = tid * 4;
        const float* fb = q.features + (size_t)b * RREG * 512;
        float4 a = make_float4(0.f, 0.f, 0.f, 0.f);
        for (int r = 0; r < RREG; ++r) {
          float w = sc[r];
          float4 v = *(const float4*)(fb + r * 512 + j0);
          a.x = fmaf(w, v.x, a.x); a.y = fmaf(w, v.y, a.y);
          a.z = fmaf(w, v.z, a.z); a.w = fmaf(w, v.w, a.w);
        }
        st_sc4(q.ctx + b * 512 + j0, a);
      }
    }
    gbar(q.bar, bix++);

    // ---- S3: gates partials (blocks 0..95 = 48 n-tiles x splitK2) ----
    if (bid < 96) {
      const int n0g = (bid >> 1) * 64, z = bid & 1;
      const bool hh = (n0g >= 1536);
      const float* A = hh ? q.h : q.ctx;
      const float* B = hh ? q.Whh : q.Wc;
      const int ldb = hh ? 512 : 1024;
      const int nb = hh ? (n0g - 1536) : n0g;
      const int tx = tid & 15, ty = tid >> 4;
      float acc[4][4] = {};
      if (!(hh && t == 0)) {
        const int lr = tid >> 3, lf = tid & 7;
        for (int k0 = z * 256; k0 < z * 256 + 256; k0 += 32) {
          {
            float4 v = ld_sc4(A + (size_t)lr * 512 + k0 + lf * 4);
            asg[lf * 4 + 0][lr] = v.x; asg[lf * 4 + 1][lr] = v.y;
            asg[lf * 4 + 2][lr] = v.z; asg[lf * 4 + 3][lr] = v.w;
            float4 w = ld_sc4(A + (size_t)(lr + 32) * 512 + k0 + lf * 4);
            asg[lf * 4 + 0][lr + 32] = w.x; asg[lf * 4 + 1][lr + 32] = w.y;
            asg[lf * 4 + 2][lr + 32] = w.z; asg[lf * 4 + 3][lr + 32] = w.w;
            float4 u = *(const float4*)(B + (size_t)(nb + lr) * ldb + k0 + lf * 4);
            bsg[lf * 4 + 0][lr] = u.x; bsg[lf * 4 + 1][lr] = u.y;
            bsg[lf * 4 + 2][lr] = u.z; bsg[lf * 4 + 3][lr] = u.w;
            float4 x = *(const float4*)(B + (size_t)(nb + lr + 32) * ldb + k0 + lf * 4);
            bsg[lf * 4 + 0][lr + 32] = x.x; bsg[lf * 4 + 1][lr + 32] = x.y;
            bsg[lf * 4 + 2][lr + 32] = x.z; bsg[lf * 4 + 3][lr + 32] = x.w;
          }
          __syncthreads();
#pragma unroll
          for (int k = 0; k < 32; ++k) {
            float4 av = *(const float4*)&asg[k][ty * 4];
            float4 bv = *(const float4*)&bsg[k][tx * 4];
            float aa[4] = {av.x, av.y, av.z, av.w};
            float bb[4] = {bv.x, bv.y, bv.z, bv.w};
#pragma unroll
            for (int i = 0; i < 4; ++i)
#pragma unroll
              for (int jj = 0; jj < 4; ++jj)
                acc[i][jj] = fmaf(aa[i], bb[jj], acc[i][jj]);
          }
          __syncthreads();
        }
      }
      float* Cp = q.P + (size_t)z * 64 * 3072;
#pragma unroll
      for (int i = 0; i < 4; ++i)
        st_sc4(Cp + (size_t)(ty * 4 + i) * 3072 + n0g + tx * 4,
               make_float4(acc[i][0], acc[i][1], acc[i][2], acc[i][3]));
    }
    gbar(q.bar, bix++);
  }
  if (bid < 32) S0(TSTEPS);   // final: h_32 -> hall[:,31]
}

extern "C" void kernel_launch(void* const* d_in, const int* in_sizes, int n_in,
                              void* d_out, int out_size, void* d_ws, size_t ws_size,
                              hipStream_t stream)
{
  const float* features = (const float*)d_in[0];
  const int*   captions = (const int*)d_in[1];
  const float* embed    = (const float*)d_in[2];
  const float* attn_W   = (const float*)d_in[3];
  const float* attn_b   = (const float*)d_in[4];
  const float* v_w      = (const float*)d_in[5];
  const float* W_ih     = (const float*)d_in[6];
  const float* W_hh     = (const float*)d_in[7];
  const float* b_ih     = (const float*)d_in[8];
  const float* b_hh     = (const float*)d_in[9];
  const float* fc_W     = (const float*)d_in[10];
  const float* fc_b     = (const float*)d_in[11];
  float* out = (float*)d_out;

  float* ws = (float*)d_ws;
  float* gxx   = ws; ws += (size_t)2048 * 1536;
  float* fproj = ws; ws += (size_t)3136 * 512;
  float* hbuf  = ws; ws += 64 * 512;
  float* ctxb  = ws; ws += 64 * 512;
  float* P     = ws; ws += (size_t)2 * 64 * 3072;
  float* Php   = ws; ws += (size_t)32 * 64 * 512;
  float* hall  = ws; ws += (size_t)2048 * 512;
  int*   bar   = (int*)ws; ws += (size_t)NSLOTS * SLOT;

  // prologue (also zeroes barrier slots for this launch)
  {
    GemmP p1{embed, W_ih, b_ih, nullptr, gxx, 2048, 1536, 512, 512, 1024, 0, 1536, captions};
    GemmP p0{features, attn_W, attn_b, nullptr, fproj, 3136, 512, 512, 512, 512, 0, 512, nullptr};
    k_prologue<<<dim3(12, 25, 2), 256, 0, stream>>>(p1, p0, bar);
  }

  // persistent recurrence; cooperative launch guarantees co-residency for the barrier
  {
    LoopP lp{gxx, b_hh, hbuf, hall, Php, P, ctxb,
             fproj, features, v_w, attn_W + (size_t)EDIM * HDIM,
             W_ih + EDIM, W_hh, bar};
    void* kargs[] = {(void*)&lp};
    hipError_t cerr = hipLaunchCooperativeKernel((const void*)k_loop2, dim3(NBLK), dim3(256),
                                                 kargs, 0, stream);
    if (cerr != hipSuccess) {
      (void)hipGetLastError();
      for (int t = 0; t < TSTEPS; ++t) {
        k_front<<<64, 512, 0, stream>>>(P, gxx, b_hh, hbuf, hall, fproj, features,
                                        v_w, attn_W + (size_t)EDIM * HDIM, ctxb, t);
        GateP g{ctxb, (t == 0) ? nullptr : hbuf, W_ih + EDIM, W_hh, P};
        k_gates<<<dim3(48, 1, 2), 256, 0, stream>>>(g);
      }
      k_front<<<64, 512, 0, stream>>>(P, gxx, b_hh, hbuf, hall, fproj, features,
                                      v_w, attn_W + (size_t)EDIM * HDIM, ctxb, TSTEPS);
    }
  }

  // vocab projection: out = hall @ fc_W + fc_b  (2048 x 10000 x 512)
  {
    GemmP p{hall, fc_W, fc_b, nullptr, out, 2048, 10000, 512, 512, 10000, 0, 10000, nullptr};
    gemm_k<false, false><<<dim3(79, 16), 256, 0, stream>>>(p);
  }
}